// Round 1
// baseline (11789.638 us; speedup 1.0000x reference)
//
#include <hip/hip_runtime.h>
#include <math.h>

// DenseLSTMForecast: B=256, T=1024, H=128, FUTURE=32.
// R8: occupancy-doubled pipeline (64 groups x 4 rows, 2 blocks/CU).
// R7 counters: VALUBusy 37%, Occupancy 21%, HBM 4.6% -> latency-bound with
// 1 WG/CU; every barrier/flag/ring-latency stall idles the CU. Fix: split
// each 8-row group into two 4-row groups -> 448 WGs, 2 co-resident
// blocks/CU so a second WG issues during the first's stalls.
// Register wall: w[128]/thread + temps ~150 unified regs (R7: 116 VGPR +
// AGPR overflow) > 128 budget for 4 waves/SIMD. Fix: 96 weights in VGPRs,
// 32 in LDS ([8][512][4] f32, contiguous-b128 conflict-free reads).
// __launch_bounds__(512,4) enforces <=128 regs -> 2 blocks/CU guaranteed
// (LDS 76,032 B x 2 = 148.5 KiB <= 160 KiB).
// Flag lines 32->16 dwords so 448 lines fit the existing 7168-dword FLAGS
// region: ws footprint byte-identical to the verified R7 layout.
// Structure otherwise identical to R7: 7 stages x 64 groups, monotonic
// per-stage flags (tid0-cached), relaxed agent-scope ring payloads, rings
// row-absolute [slot][256 rows][...], anti-deps gated on head flag.
//   s0 c1-core   : g1 = xw1*x+b1 + Whh1*h1           -> RH1 ring
//   s1 c2-helper : p2 = xw2*x+b2 + Wih2[:,1:]*h1(t)  -> RP2 ring
//   s2 c2-core   : g2 = p2 + Whh2*h2                 -> RH2 ring
//   s3 c3-helperA: pA = xw3*x+b3 + Wih3[:,1:129]*h1  -> RP3A ring
//   s4 c3-helperB: pB = Wih3[:,129:257]*h2           -> RP3B ring
//   s5 c3-core   : g3 = pA+pB + Whh3*h3              -> RH3 ring
//   s6 head      : o = Wlin.[x,h1,h2,h3]+b           -> RO ring + out

#define TSEQ 1024
#define HH   128
#define TT   1056
#define NG   64            // groups
#define ROWS 4             // batch rows per group

// ---- ws dword offsets (identical to R7) ----
#define PLANES   0                 // 6 planes x [128 k][512 g] fp32
#define SCAL     393216            // xw1,xw2,xw3,bs1,bs2,bs3 (512 each)
#define WLIN     396288            // Wlin[0..384], [385]=b_lin, pad 512
#define XT       396800            // x transposed [1024][256]
#define RH1      658944            // h rings: [16][256][128] fp32
#define RH2      1183232
#define RH3      1707520
#define RO       2231808           // o ring [16][256] fp32
#define RP2      2235904           // partial rings: [8][256][512] fp32
#define RP3A     3284480
#define RP3B     4333056
#define FLAGS    5381632           // 448 x 16-dword lines = 7168 dwords
#define PREP_TOT 666112            // 658944 + 7168 (flags zeroing)

#define RH1_64 (RH1/2)
#define RH2_64 (RH2/2)
#define RH3_64 (RH3/2)

// ---- LDS layout inside SB (core view; helper/head reuse as union) ----
#define SB_WLDS  0                 // [8][512][4] f32 = 65536 B (k=96..127)
#define SB_GS    65536             // core: [4][512] f32 = 8192 B
#define SB_HOWN  73728             // core: [4][128] f32 = 2048 B
#define SB_XS    75776             // core: [4] f32
#define SB_SIZE  76032

typedef unsigned long long u64;

__device__ __forceinline__ float sigmoidf_(float v) {
  return 1.0f / (1.0f + expf(-v));
}

__device__ __forceinline__ void wait_c(unsigned* p, unsigned tgt, unsigned& cached) {
  if (cached >= tgt) return;
  unsigned v = __hip_atomic_load(p, __ATOMIC_ACQUIRE, __HIP_MEMORY_SCOPE_AGENT);
  while (v < tgt) {
    __builtin_amdgcn_s_sleep(1);
    v = __hip_atomic_load(p, __ATOMIC_ACQUIRE, __HIP_MEMORY_SCOPE_AGENT);
  }
  cached = v;
}

// ---------------------------------------------------------------------------
__global__ void prep_kernel(const float* __restrict__ x,
                            const float* __restrict__ Wih1, const float* __restrict__ Whh1,
                            const float* __restrict__ bih1, const float* __restrict__ bhh1,
                            const float* __restrict__ Wih2, const float* __restrict__ Whh2,
                            const float* __restrict__ bih2, const float* __restrict__ bhh2,
                            const float* __restrict__ Wih3, const float* __restrict__ Whh3,
                            const float* __restrict__ bih3, const float* __restrict__ bhh3,
                            const float* __restrict__ Wlin, const float* __restrict__ blin,
                            float* __restrict__ ws) {
  int idx = blockIdx.x * 256 + threadIdx.x;
  if (idx < SCAL) {
    int p = idx >> 16;            // plane
    int rem = idx & 65535;
    int k = rem >> 9, g = rem & 511;
    float v;
    switch (p) {
      case 0:  v = Whh1[g * HH + k];         break;
      case 1:  v = Wih2[g * 129 + 1 + k];    break;
      case 2:  v = Whh2[g * HH + k];         break;
      case 3:  v = Wih3[g * 257 + 1 + k];    break;
      case 4:  v = Wih3[g * 257 + 129 + k];  break;
      default: v = Whh3[g * HH + k];         break;
    }
    ws[idx] = v;
  } else if (idx < WLIN) {
    int r = idx - SCAL;
    float v;
    if      (r < 512)  v = Wih1[r];
    else if (r < 1024) v = Wih2[(r - 512) * 129];
    else if (r < 1536) v = Wih3[(r - 1024) * 257];
    else if (r < 2048) v = bih1[r - 1536] + bhh1[r - 1536];
    else if (r < 2560) v = bih2[r - 2048] + bhh2[r - 2048];
    else               v = bih3[r - 2560] + bhh3[r - 2560];
    ws[idx] = v;
  } else if (idx < XT) {
    int j = idx - WLIN;
    ws[idx] = (j < 385) ? Wlin[j] : (j == 385 ? blin[0] : 0.0f);
  } else if (idx < RH1) {
    int j = idx - XT;
    int t = j >> 8, r = j & 255;
    ws[idx] = x[r * TSEQ + t];
  } else if (idx < PREP_TOT) {
    ws[FLAGS + (idx - RH1)] = 0.0f;   // zero flag lines (ws is poisoned)
  }
}

// ---------------------------------------------------------------------------
// Hybrid k-loop: 96 weights from VGPRs, 32 from LDS; h broadcast from LDS.
__device__ __forceinline__ void dot128h(const float* __restrict__ w,
                                        const float* __restrict__ wlds,
                                        const float* __restrict__ hbuf,
                                        int tid, float acc[ROWS]) {
  #pragma unroll
  for (int k4 = 0; k4 < 24; ++k4) {
    const float w0 = w[4 * k4], w1 = w[4 * k4 + 1];
    const float w2 = w[4 * k4 + 2], w3 = w[4 * k4 + 3];
    #pragma unroll
    for (int a = 0; a < ROWS; ++a) {
      const float4 h4 = *(const float4*)&hbuf[a * HH + k4 * 4];
      acc[a] = fmaf(w0, h4.x, fmaf(w1, h4.y, fmaf(w2, h4.z, fmaf(w3, h4.w, acc[a]))));
    }
  }
  #pragma unroll
  for (int k4 = 0; k4 < 8; ++k4) {
    const float4 w4 = *(const float4*)&wlds[(size_t)(k4 * 512 + tid) * 4];
    #pragma unroll
    for (int a = 0; a < ROWS; ++a) {
      const float4 h4 = *(const float4*)&hbuf[a * HH + (24 + k4) * 4];
      acc[a] = fmaf(w4.x, h4.x, fmaf(w4.y, h4.y, fmaf(w4.z, h4.z, fmaf(w4.w, h4.w, acc[a]))));
    }
  }
}

// Stage-local weight load: k=0..95 into regs, k=96..127 into LDS.
__device__ __forceinline__ void load_w(const float* __restrict__ wsm, int PB,
                                       int tid, float w[96], float* wlds) {
  #pragma unroll
  for (int k = 0; k < 96; ++k)
    w[k] = wsm[(size_t)PB * 65536 + (size_t)k * 512 + tid];
  #pragma unroll
  for (int k4 = 0; k4 < 8; ++k4) {
    float4 v;
    v.x = wsm[(size_t)PB * 65536 + (size_t)(96 + k4 * 4 + 0) * 512 + tid];
    v.y = wsm[(size_t)PB * 65536 + (size_t)(96 + k4 * 4 + 1) * 512 + tid];
    v.z = wsm[(size_t)PB * 65536 + (size_t)(96 + k4 * 4 + 2) * 512 + tid];
    v.w = wsm[(size_t)PB * 65536 + (size_t)(96 + k4 * 4 + 3) * 512 + tid];
    *(float4*)&wlds[(size_t)(k4 * 512 + tid) * 4] = v;
  }
}

// ---------------------------------------------------------------------------
// Core stage: gates = [partials or x-term] + Whh*h_own; activation; publish h.
template <int SSELF, int SWA, int SWB, int NP, int XF, int PB, int PR1, int PR2, int DRH64>
__device__ void core_stage(float* __restrict__ wsm, char* SB, int g) {
  const int tid = threadIdx.x;
  const int r0 = g * ROWS;
  float* wlds = (float*)(SB + SB_WLDS);
  float* gs   = (float*)(SB + SB_GS);       // [4][512]
  float* hown = (float*)(SB + SB_HOWN);     // [4][128]
  float* xs   = (float*)(SB + SB_XS);       // [4]

  u64* ws64 = (u64*)wsm;
  unsigned* flagb = (unsigned*)wsm + FLAGS;
  unsigned* Fself = flagb + (size_t)(SSELF * NG + g) * 16;
  unsigned* Fh    = flagb + (size_t)(6 * NG + g) * 16;
  unsigned ca = 0, cb = 0, ch = 0;

  float w[96];
  load_w(wsm, PB, tid, w, wlds);
  const float xwv = XF ? wsm[SCAL + tid] : 0.f;
  const float bsv = XF ? wsm[SCAL + 1536 + tid] : 0.f;

  hown[tid] = 0.f;                          // 4*128 = 512 = blockDim
  float cst = 0.f;
  __syncthreads();

  for (int t = 0; t < TT; ++t) {
    if (tid == 0) {
      if constexpr (SWA >= 0)
        wait_c(flagb + (size_t)(SWA * NG + g) * 16, (unsigned)(t + 1), ca);
      if constexpr (SWB >= 0)
        wait_c(flagb + (size_t)(SWB * NG + g) * 16, (unsigned)(t + 1), cb);
      unsigned ht = (t >= 15) ? (unsigned)(t - 14) : 0u;
      if (XF && t >= TSEQ && (unsigned)t > ht) ht = (unsigned)t;
      if (ht) wait_c(Fh, ht, ch);
    }
    __syncthreads();
    const int slot = t & 15;

    if (XF) {
      if (tid < ROWS) {
        float xv;
        if (t < TSEQ) {
          xv = wsm[XT + (size_t)t * 256 + r0 + tid];
        } else {
          unsigned u = __hip_atomic_load(
              (unsigned*)wsm + RO + (size_t)((t - 1) & 15) * 256 + r0 + tid,
              __ATOMIC_RELAXED, __HIP_MEMORY_SCOPE_AGENT);
          xv = __builtin_bit_cast(float, u);
        }
        xs[tid] = xv;
      }
      __syncthreads();
    }

    float acc[ROWS];
    if constexpr (NP == 0) {
      #pragma unroll
      for (int a = 0; a < ROWS; ++a) acc[a] = fmaf(xwv, xs[a], bsv);
    } else {
      #pragma unroll
      for (int a = 0; a < ROWS; ++a) {
        unsigned u = __hip_atomic_load(
            (unsigned*)wsm + PR1 + (size_t)(t & 7) * 131072 + (size_t)(r0 + a) * 512 + tid,
            __ATOMIC_RELAXED, __HIP_MEMORY_SCOPE_AGENT);
        acc[a] = __builtin_bit_cast(float, u);
      }
      if constexpr (NP == 2) {
        #pragma unroll
        for (int a = 0; a < ROWS; ++a) {
          unsigned u = __hip_atomic_load(
              (unsigned*)wsm + PR2 + (size_t)(t & 7) * 131072 + (size_t)(r0 + a) * 512 + tid,
              __ATOMIC_RELAXED, __HIP_MEMORY_SCOPE_AGENT);
          acc[a] += __builtin_bit_cast(float, u);
        }
      }
    }

    dot128h(w, wlds, hown, tid, acc);

    #pragma unroll
    for (int a = 0; a < ROWS; ++a) gs[a * 512 + tid] = acc[a];
    __syncthreads();

    // activation: 512 units / 512 thr = 1 each
    {
      const int row = tid >> 7, u = tid & 127;
      const float gi = gs[row * 512 + u];
      const float gf = gs[row * 512 + 128 + u];
      const float gg = gs[row * 512 + 256 + u];
      const float go = gs[row * 512 + 384 + u];
      const float c0 = sigmoidf_(gf) * cst + sigmoidf_(gi) * tanhf(gg);
      cst = c0;
      hown[row * HH + u] = sigmoidf_(go) * tanhf(c0);
    }
    __syncthreads();

    // publish h(t): 4 rows x 128 = 256 u64
    if (tid < 256) {
      const int a = tid >> 6, up = tid & 63;
      u64 v = *(const u64*)&hown[a * HH + up * 2];
      __hip_atomic_store(
          ws64 + DRH64 + (size_t)slot * 16384 + (size_t)(r0 + a) * 64 + up, v,
          __ATOMIC_RELAXED, __HIP_MEMORY_SCOPE_AGENT);
    }
    __syncthreads();                 // vmcnt drained at barrier
    if (tid == 0)
      __hip_atomic_fetch_add(Fself, 1u, __ATOMIC_RELAXED, __HIP_MEMORY_SCOPE_AGENT);
  }
}

// ---------------------------------------------------------------------------
// Helper stage: partial = [x-term+bias if XF] + Wpart * h_src(t); publish.
template <int SSELF, int SW, int XF, int PB, int SI, int SRH64, int DRP>
__device__ void helper_stage(float* __restrict__ wsm, char* SB, int g) {
  const int tid = threadIdx.x;
  const int r0 = g * ROWS;
  float* wlds = (float*)(SB + SB_WLDS);
  float* hin  = (float*)(SB + 65536);       // [4][128]
  float* xs   = (float*)(SB + 65536 + 2048);

  u64* ws64 = (u64*)wsm;
  unsigned* flagb = (unsigned*)wsm + FLAGS;
  unsigned* Fself = flagb + (size_t)(SSELF * NG + g) * 16;
  unsigned* Fw    = flagb + (size_t)(SW * NG + g) * 16;
  unsigned* Fh    = flagb + (size_t)(6 * NG + g) * 16;
  unsigned cw = 0, ch = 0;

  float w[96];
  load_w(wsm, PB, tid, w, wlds);
  const float xwv = XF ? wsm[SCAL + SI * 512 + tid] : 0.f;
  const float bsv = XF ? wsm[SCAL + 1536 + SI * 512 + tid] : 0.f;
  __syncthreads();

  for (int t = 0; t < TT; ++t) {
    if (tid == 0) {
      wait_c(Fw, (unsigned)(t + 1), cw);
      unsigned ht = (t >= 7) ? (unsigned)(t - 6) : 0u;
      if (XF && t >= TSEQ && (unsigned)t > ht) ht = (unsigned)t;
      if (ht) wait_c(Fh, ht, ch);
    }
    __syncthreads();
    const int slot = t & 15;

    if (XF) {
      if (tid < ROWS) {
        float xv;
        if (t < TSEQ) {
          xv = wsm[XT + (size_t)t * 256 + r0 + tid];
        } else {
          unsigned u = __hip_atomic_load(
              (unsigned*)wsm + RO + (size_t)((t - 1) & 15) * 256 + r0 + tid,
              __ATOMIC_RELAXED, __HIP_MEMORY_SCOPE_AGENT);
          xv = __builtin_bit_cast(float, u);
        }
        xs[tid] = xv;
      }
    }
    // stage h_src(t): 256 u64
    if (tid < 256) {
      const int a = tid >> 6, up = tid & 63;
      u64 v = __hip_atomic_load(
          ws64 + SRH64 + (size_t)slot * 16384 + (size_t)(r0 + a) * 64 + up,
          __ATOMIC_RELAXED, __HIP_MEMORY_SCOPE_AGENT);
      *(u64*)&hin[a * HH + up * 2] = v;
    }
    __syncthreads();

    float acc[ROWS];
    #pragma unroll
    for (int a = 0; a < ROWS; ++a) acc[a] = XF ? fmaf(xwv, xs[a], bsv) : 0.f;

    dot128h(w, wlds, hin, tid, acc);

    #pragma unroll
    for (int a = 0; a < ROWS; ++a)
      __hip_atomic_store(
          (unsigned*)wsm + DRP + (size_t)(t & 7) * 131072 + (size_t)(r0 + a) * 512 + tid,
          __builtin_bit_cast(unsigned, acc[a]),
          __ATOMIC_RELAXED, __HIP_MEMORY_SCOPE_AGENT);
    __syncthreads();                 // vmcnt drained
    if (tid == 0)
      __hip_atomic_fetch_add(Fself, 1u, __ATOMIC_RELAXED, __HIP_MEMORY_SCOPE_AGENT);
  }
}

// ---------------------------------------------------------------------------
__device__ void head_stage(float* __restrict__ wsm, char* SB, int g,
                           float* __restrict__ out) {
  const int tid = threadIdx.x;
  const int r0 = g * ROWS;
  float* wl   = (float*)SB;                 // [512]
  float* hin  = (float*)(SB + 2048);        // [3][4][128]
  float* obuf = (float*)(SB + 8192);        // [4][32]
  float* xv   = (float*)(SB + 8704);        // [4]

  u64* ws64 = (u64*)wsm;
  unsigned* flagb = (unsigned*)wsm + FLAGS;
  unsigned* Fself = flagb + (size_t)(6 * NG + g) * 16;
  unsigned* Fc3   = flagb + (size_t)(5 * NG + g) * 16;
  unsigned c3c = 0;

  wl[tid] = wsm[WLIN + tid];
  if (tid < ROWS) xv[tid] = wsm[XT + r0 + tid];
  __syncthreads();

  const int row = (tid >> 6) & 3, lane = tid & 63;

  for (int t = 0; t < TT; ++t) {
    if (tid == 0) wait_c(Fc3, (unsigned)(t + 1), c3c);
    __syncthreads();
    const int slot = t & 15;

    for (int i = tid; i < 768; i += 512) {
      const int s = i >> 8, rem = i & 255;
      const int a = rem >> 6, up = rem & 63;
      const size_t base = (s == 0) ? (size_t)RH1_64 : (s == 1) ? (size_t)RH2_64 : (size_t)RH3_64;
      u64 v = __hip_atomic_load(
          ws64 + base + (size_t)slot * 16384 + (size_t)(r0 + a) * 64 + up,
          __ATOMIC_RELAXED, __HIP_MEMORY_SCOPE_AGENT);
      *(u64*)&hin[(s * ROWS + a) * HH + up * 2] = v;
    }
    __syncthreads();

    if (tid < 256) {
      float s = 0.f;
      #pragma unroll
      for (int q = 0; q < 6; ++q) {
        const int j = lane + 64 * q;          // 0..383
        const int si = j >> 7, u = j & 127;
        s = fmaf(wl[1 + j], hin[(si * ROWS + row) * HH + u], s);
      }
      #pragma unroll
      for (int off = 32; off > 0; off >>= 1) s += __shfl_down(s, off, 64);
      if (lane == 0) {
        const float o = s + fmaf(wl[0], xv[row], wl[385]);
        obuf[row * 32 + (t & 31)] = o;
        __hip_atomic_store((unsigned*)wsm + RO + (size_t)slot * 256 + r0 + row,
                           __builtin_bit_cast(unsigned, o),
                           __ATOMIC_RELAXED, __HIP_MEMORY_SCOPE_AGENT);
        xv[row] = (t + 1 < TSEQ) ? wsm[XT + (size_t)(t + 1) * 256 + r0 + row] : o;
      }
    }
    __syncthreads();                 // drain o-store + obuf
    if (tid == 0)
      __hip_atomic_fetch_add(Fself, 1u, __ATOMIC_RELAXED, __HIP_MEMORY_SCOPE_AGENT);

    if ((t & 31) == 31) {
      const int tb = t - 31;
      if (tid < 128) {
        const int a = tid >> 5, m = tid & 31;
        out[(size_t)(r0 + a) * TT + tb + m] = obuf[a * 32 + m];
      }
    }
  }
}

// ---------------------------------------------------------------------------
__global__ __launch_bounds__(512, 4)
void lstm_kernel(float* __restrict__ wsm, float* __restrict__ out) {
  __shared__ __align__(16) char SB[SB_SIZE];
  const int s = blockIdx.x >> 6, g = blockIdx.x & 63;
  switch (s) {
    case 0: core_stage<0, -1, -1, 0, 1, 0, 0, 0, RH1_64>(wsm, SB, g); break;
    case 1: helper_stage<1, 0, 1, 1, 1, RH1_64, RP2>(wsm, SB, g); break;
    case 2: core_stage<2, 1, -1, 1, 0, 2, RP2, 0, RH2_64>(wsm, SB, g); break;
    case 3: helper_stage<3, 0, 1, 3, 2, RH1_64, RP3A>(wsm, SB, g); break;
    case 4: helper_stage<4, 2, 0, 4, 0, RH2_64, RP3B>(wsm, SB, g); break;
    case 5: core_stage<5, 3, 4, 2, 0, 5, RP3A, RP3B, RH3_64>(wsm, SB, g); break;
    default: head_stage(wsm, SB, g, out); break;
  }
}

// ---------------------------------------------------------------------------
extern "C" void kernel_launch(void* const* d_in, const int* in_sizes, int n_in,
                              void* d_out, int out_size, void* d_ws, size_t ws_size,
                              hipStream_t stream) {
  const float* x    = (const float*)d_in[0];
  const float* Wih1 = (const float*)d_in[1];
  const float* Whh1 = (const float*)d_in[2];
  const float* bih1 = (const float*)d_in[3];
  const float* bhh1 = (const float*)d_in[4];
  const float* Wih2 = (const float*)d_in[5];
  const float* Whh2 = (const float*)d_in[6];
  const float* bih2 = (const float*)d_in[7];
  const float* bhh2 = (const float*)d_in[8];
  const float* Wih3 = (const float*)d_in[9];
  const float* Whh3 = (const float*)d_in[10];
  const float* bih3 = (const float*)d_in[11];
  const float* bhh3 = (const float*)d_in[12];
  const float* Wlin = (const float*)d_in[13];
  const float* blin = (const float*)d_in[14];
  float* ws  = (float*)d_ws;
  float* out = (float*)d_out;

  prep_kernel<<<PREP_TOT / 256, 256, 0, stream>>>(
      x, Wih1, Whh1, bih1, bhh1, Wih2, Whh2, bih2, bhh2,
      Wih3, Whh3, bih3, bhh3, Wlin, blin, ws);
  lstm_kernel<<<7 * NG, 512, 0, stream>>>(ws, out);
}